// Round 9
// baseline (98.557 us; speedup 1.0000x reference)
//
#include <hip/hip_runtime.h>
#include <cstdint>

#define BB     4096
#define TT     96
#define NC     85
#define BLANKC 84
#define DD     64
#define ALPHA  0.05f
#define BT     (BB * TT)      // 393216
#define NF4    (TT * NC / 4)  // 2040 float4 per batch row
#define NBLK   512            // fused-kernel blocks (2/CU)
#define RPB    (BB / NBLK)    // 8 batch rows per block
#define FSTR   73             // F-array row stride (odd: spreads banks)

// ---------------------------------------------------------------------------
// Kernel 1 (fused, persistent): block = 8 batch rows, one-row-ahead register
// pipeline for BOTH streams (preds 4xfloat4 + features 12xdword per thread,
// double-buffered fc/fn). 3 barriers per row:
//   B: commit preds regs->rows, raw labels->labraw[par]; ISSUE row r+1 preds
//      + features + labels          C:sync
//   D: quarter-scan rows -> sv/sc; 12 thr precompute octet dup flags
//                                   E:sync
//   F: combine quarters for t,t+1 (strict > keeps lowest col), CTC mask,
//      lab_ls pack, LDS histogram   G:sync
//   H: 12 feature steps from REGISTERS — wave w owns dims w*8..w*8+7, lanes =
//      8 positions x 8 dims; all waves write disjoint columns of one shared
//      F[85][73]: plain += when octet labels distinct, LDS-atomic otherwise.
// Barrier A eliminated: labraw is parity-double-buffered; rows/sv/sc/dupflag
// hazards are covered by C (H(r-1) completes before any wave passes C(r)).
// Epilogue: F -> updp[blk], hist -> hpartT[class][blk], |f|^2 -> lossp[blk].
// NO global atomics; labm never touches HBM.
// ---------------------------------------------------------------------------
template<int C0, int C1>
__device__ inline void scanR(const float* __restrict__ row, float& bv, int& bc) {
    bv = row[C0]; bc = C0;
#pragma unroll
    for (int c = C0 + 1; c < C1; ++c) {
        float v = row[c];
        if (v > bv) { bv = v; bc = c; }
    }
}

__global__ __launch_bounds__(512, 4) void k_fused(const float4* __restrict__ p4,
                                                  const int* __restrict__ labels,
                                                  const float* __restrict__ feat,
                                                  float* __restrict__ updp,
                                                  int* __restrict__ hpartT,
                                                  float* __restrict__ lossp,
                                                  float* __restrict__ out) {
    __shared__ float rows[TT * NC];                // 32640 B
    __shared__ float Farr[NC * FSTR];              // 24820 B
    __shared__ float sv[4 * TT];                   // 1536 B
    __shared__ int   sc[4 * TT];                   // 1536 B
    __shared__ unsigned lab_ls[TT];                // masked words (F->H)
    __shared__ int   labraw[2][TT];                // raw labels, parity dbuf
    __shared__ int   dupflag[12];
    __shared__ int   h[NC];
    __shared__ float lred[8];

    int tid  = threadIdx.x;
    int blk  = blockIdx.x;
    int lane = tid & 63;
    int w    = tid >> 6;
    int sub  = lane >> 3;                          // position-in-octet
    int l8   = lane & 7;
    int dim  = (w << 3) | l8;                      // wave owns 8 dims

    for (int i = tid; i < NC * FSTR; i += 512) Farr[i] = 0.f;
    if (tid < NC) h[tid] = 0;
    if (blk == 0 && tid == 500) out[0] = 0.f;

    // prologue: issue row 0 (preds + labels + features)
    int row0 = blk * RPB;
    const float4* s0 = p4 + (size_t)row0 * NF4;
    float4 v0 = s0[tid];
    float4 v1 = s0[tid + 512];
    float4 v2 = s0[tid + 1024];
    float4 v3 = s0[tid + 1536 < NF4 ? tid + 1536 : NF4 - 1];
    int lcur = (tid < TT) ? labels[row0 * TT + tid] : 0;
    float fc[12];
    {
        const float* fb = feat + (size_t)row0 * TT * DD;
#pragma unroll
        for (int s = 0; s < 12; ++s) fc[s] = fb[(s * 8 + sub) * DD + dim];
    }
    float lsum = 0.f;

    for (int r8 = 0; r8 < RPB; ++r8) {
        int row = row0 + r8;
        int par = r8 & 1;
        // B: commit preds regs -> LDS, labels -> labraw[par]; issue row r+1
        float4* r4 = (float4*)rows;
        r4[tid]        = v0;
        r4[tid + 512]  = v1;
        r4[tid + 1024] = v2;
        if (tid + 1536 < NF4) r4[tid + 1536] = v3;
        if (tid < TT) labraw[par][tid] = lcur;
        int lnext = 0;
        float fn[12];
        if (r8 + 1 < RPB) {
            const float4* sn = p4 + (size_t)(row + 1) * NF4;
            v0 = sn[tid];
            v1 = sn[tid + 512];
            v2 = sn[tid + 1024];
            v3 = sn[tid + 1536 < NF4 ? tid + 1536 : NF4 - 1];
            if (tid < TT) lnext = labels[(row + 1) * TT + tid];
            const float* fb = feat + (size_t)(row + 1) * TT * DD;
#pragma unroll
            for (int s = 0; s < 12; ++s) fn[s] = fb[(s * 8 + sub) * DD + dim];
        }
        __syncthreads();                           // C: rows/labraw visible
        // D: quarter scan (q = wave>>1, uniform) + octet dup precompute
        {
            int q = tid >> 7, r = tid & 127;
            if (r < TT) {
                const float* rw = rows + r * NC;
                float bv; int bc;
                switch (q) {
                    case 0:  scanR< 0, 22>(rw, bv, bc); break;
                    case 1:  scanR<22, 43>(rw, bv, bc); break;
                    case 2:  scanR<43, 64>(rw, bv, bc); break;
                    default: scanR<64, 85>(rw, bv, bc); break;
                }
                sv[q * TT + r] = bv; sc[q * TT + r] = bc;
            }
            if (tid < 12) {
                int l[8];
#pragma unroll
                for (int k = 0; k < 8; ++k) l[k] = labraw[par][tid * 8 + k];
                int d = 0;
#pragma unroll
                for (int a = 0; a < 8; ++a)
#pragma unroll
                    for (int b2 = a + 1; b2 < 8; ++b2) d |= (l[a] == l[b2]);
                dupflag[tid] = d;
            }
        }
        __syncthreads();                           // E: sv/sc/dupflag visible
        // F: combine t and t+1, mask, pack lab_ls, histogram
        if (tid < TT) {
            int t1 = (tid + 1 < TT) ? tid + 1 : tid;
            float bv = sv[tid];  int bc = sc[tid];
            float bw = sv[t1];   int bd = sc[t1];
#pragma unroll
            for (int q = 1; q < 4; ++q) {
                float a = sv[q * TT + tid]; int c = sc[q * TT + tid];
                if (a > bv) { bv = a; bc = c; }
                float a1 = sv[q * TT + t1]; int c1 = sc[q * TT + t1];
                if (a1 > bw) { bw = a1; bd = c1; }
            }
            int m = (bc != BLANKC) && (tid == TT - 1 || bc != bd);
            lab_ls[tid] = (unsigned)lcur | ((unsigned)m << 31);
            atomicAdd(&h[lcur], m);                // LDS only
        }
        lcur = lnext;
        __syncthreads();                           // G: lab_ls final
        // H: 12 feature steps, registers only
        {
            int dfl[12];
#pragma unroll
            for (int k = 0; k < 12; ++k) dfl[k] = dupflag[k];
#pragma unroll
            for (int s = 0; s < 12; ++s) {
                unsigned lw = lab_ls[s * 8 + sub];
                float m = (float)(lw >> 31);
                int  la = (int)(lw & 0x7fffffffu);
                float c = m * fc[s];
                lsum = fmaf(c, fc[s], lsum);
                int a = la * FSTR + dim;
                if (dfl[s]) atomicAdd(&Farr[a], c);
                else        Farr[a] += c;
            }
        }
        if (r8 + 1 < RPB) {
#pragma unroll
            for (int s = 0; s < 12; ++s) fc[s] = fn[s];
        }
    }
    __syncthreads();
    // epilogue: flush F, histogram, loss partial
    float* myp = updp + (size_t)blk * (NC * DD);
    for (int i = tid; i < NC * DD; i += 512)
        myp[i] = Farr[(i >> 6) * FSTR + (i & 63)];
    if (tid < NC) hpartT[tid * NBLK + blk] = h[tid];
#pragma unroll
    for (int off = 32; off; off >>= 1) lsum += __shfl_xor(lsum, off);
    if (lane == 0) lred[w] = lsum;
    __syncthreads();
    if (tid == 0) {
        float s = 0.f;
#pragma unroll
        for (int ww = 0; ww < 8; ++ww) s += lred[ww];
        lossp[blk] = s;
    }
}

// ---------------------------------------------------------------------------
// Kernel 2: grid NC*4+1. Block (j,q): counts[j] = coalesced sum of
// hpartT[j][0..NBLK), then F over NBLK partials for 16 dims, write centers,
// atomic-add 0.5*loss piece into out[0]. Last block reduces Sfeat.
// ---------------------------------------------------------------------------
__global__ __launch_bounds__(256) void k_reduce(const float* __restrict__ updp,
                                                const float* __restrict__ lossp,
                                                const float* __restrict__ centers,
                                                const int* __restrict__ hpartT,
                                                float* __restrict__ out) {
    __shared__ float sred[256];
    __shared__ float sr[4];
    __shared__ int   scnt;
    int tid = threadIdx.x;
    int bid = blockIdx.x;
    if (bid < NC * 4) {
        int j = bid >> 2, q = bid & 3;
        int cs = 0;
        for (int t = tid; t < NBLK; t += 256) cs += hpartT[j * NBLK + t];
#pragma unroll
        for (int off = 32; off; off >>= 1) cs += __shfl_xor(cs, off);
        int lane = tid & 63, wv = tid >> 6;
        if (lane == 0) ((int*)sred)[wv] = cs;
        __syncthreads();
        if (tid == 0)
            scnt = ((int*)sred)[0] + ((int*)sred)[1] +
                   ((int*)sred)[2] + ((int*)sred)[3];
        __syncthreads();
        float cnt = (float)scnt;
        int i = tid & 15;
        int c16 = tid >> 4;
        int per = NBLK >> 4;                       // 32
        int col = j * DD + q * 16 + i;
        float s = 0.f;
        for (int b = c16 * per; b < (c16 + 1) * per; ++b)
            s += updp[(size_t)b * (NC * DD) + col];
        sred[tid] = s;
        __syncthreads();
        if (tid < 16) {
            float F = 0.f;
#pragma unroll
            for (int cc = 0; cc < 16; ++cc) F += sred[cc * 16 + i];
            float c   = centers[col];
            float scale = ALPHA / (1.f + cnt);
            out[1 + col] = c - scale * (cnt * c - F);
            float lp = cnt * c * c - 2.f * c * F;
#pragma unroll
            for (int off = 8; off; off >>= 1) lp += __shfl_xor(lp, off);
            if (i == 0) atomicAdd(&out[0], 0.5f * lp);
        }
    } else {
        float s = 0.f;
        for (int t = tid; t < NBLK; t += 256) s += lossp[t];
#pragma unroll
        for (int off = 32; off; off >>= 1) s += __shfl_xor(s, off);
        int lane = tid & 63, wv = tid >> 6;
        if (lane == 0) sr[wv] = s;
        __syncthreads();
        if (tid == 0) atomicAdd(&out[0], 0.5f * (sr[0] + sr[1] + sr[2] + sr[3]));
    }
}

// ---------------------------------------------------------------------------
extern "C" void kernel_launch(void* const* d_in, const int* in_sizes, int n_in,
                              void* d_out, int out_size, void* d_ws, size_t ws_size,
                              hipStream_t stream) {
    const float* preds    = (const float*)d_in[0];
    const float* features = (const float*)d_in[1];
    const int*   labels   = (const int*)d_in[2];
    const float* centers  = (const float*)d_in[3];
    float* out = (float*)d_out;

    char* ws = (char*)d_ws;
    float* updp   = (float*)ws;                          // NBLK*NC*DD f (11.1 MB)
    int*   hpartT = (int*)(ws + (size_t)NBLK * NC * DD * 4);   // NC*NBLK ints
    float* lossp  = (float*)(ws + (size_t)NBLK * NC * DD * 4
                                + (size_t)NC * NBLK * 4);      // NBLK floats

    k_fused<<<NBLK, 512, 0, stream>>>((const float4*)preds, labels, features,
                                      updp, hpartT, lossp, out);
    k_reduce<<<NC * 4 + 1, 256, 0, stream>>>(updp, lossp, centers, hpartT, out);
}

// Round 10
// 83.293 us; speedup vs baseline: 1.1833x; 1.1833x over previous
//
#include <hip/hip_runtime.h>
#include <cstdint>

#define BB     4096
#define TT     96
#define NC     85
#define BLANKC 84
#define DD     64
#define ALPHA  0.05f
#define BT     (BB * TT)      // 393216
#define SLICE_F (NC * 17)     // 1445 floats per wave-private slice (pad 16->17)
#define NF4    (TT * NC / 4)  // 2040 float4 per batch row

// ---------------------------------------------------------------------------
// Kernel 1: fused argmax + CTC mask + per-block histogram (R7 verbatim).
// Block = one batch row. Stage via exactly-4 float4/thread, scan stride-85,
// combine with lowest-col tie-break, mask from in-block pls[t+1], histogram
// in LDS -> transposed hpartT[class][block]. NO global atomics.
// ---------------------------------------------------------------------------
template<int C0, int C1>
__device__ inline void scanR(const float* __restrict__ row, float& bv, int& bc) {
    bv = row[C0]; bc = C0;
#pragma unroll
    for (int c = C0 + 1; c < C1; ++c) {
        float v = row[c];
        if (v > bv) { bv = v; bc = c; }
    }
}

__global__ __launch_bounds__(512) void k_amask(const float4* __restrict__ p4,
                                               const int* __restrict__ labels,
                                               unsigned* __restrict__ labm,
                                               int* __restrict__ hpartT,
                                               float* __restrict__ out) {
    __shared__ float rows[TT * NC];                // 32640 B
    __shared__ float sv[4 * TT];
    __shared__ int   sc[4 * TT];
    __shared__ int   pls[TT];
    __shared__ int   h[NC];
    int tid = threadIdx.x;
    int b   = blockIdx.x;
    if (tid < NC) h[tid] = 0;
    if (b == 0 && tid == 480) out[0] = 0.f;

    const float4* src = p4 + (size_t)b * NF4;
    float4* r4 = (float4*)rows;
    float4 v[4];
#pragma unroll
    for (int k = 0; k < 4; ++k)
        v[k] = src[min(tid + k * 512, NF4 - 1)];
#pragma unroll
    for (int k = 0; k < 4; ++k) {
        int i = tid + k * 512;
        if (i < NF4) r4[i] = v[k];
    }
    __syncthreads();

    int q = tid >> 7, r = tid & 127;               // q wave-uniform
    if (r < TT) {
        const float* row = rows + r * NC;
        float bv; int bc;
        switch (q) {
            case 0:  scanR< 0, 22>(row, bv, bc); break;
            case 1:  scanR<22, 43>(row, bv, bc); break;
            case 2:  scanR<43, 64>(row, bv, bc); break;
            default: scanR<64, 85>(row, bv, bc); break;
        }
        sv[q * TT + r] = bv; sc[q * TT + r] = bc;
    }
    __syncthreads();
    if (tid < TT) {
        float bv = sv[tid]; int bc = sc[tid];
#pragma unroll
        for (int qq = 1; qq < 4; ++qq) {
            float v2 = sv[qq * TT + tid];
            int   c2 = sc[qq * TT + tid];
            if (v2 > bv) { bv = v2; bc = c2; }     // strict >: lower col wins ties
        }
        pls[tid] = bc;
    }
    __syncthreads();
    if (tid < TT) {
        int p = pls[tid];
        int m = (p != BLANKC) && (tid == TT - 1 || p != pls[tid + 1]);
        int lab = labels[b * TT + tid];
        labm[b * TT + tid] = (unsigned)lab | ((unsigned)m << 31);
        atomicAdd(&h[lab], m);                     // LDS only
    }
    __syncthreads();
    if (tid < NC) hpartT[tid * BB + b] = h[tid];   // unconditional, transposed
}

// ---------------------------------------------------------------------------
// Kernel 2: masked feature segment-sum with an 8-load-deep register pipeline.
// 8 waves/block; wave w owns dim-quad dq=w&3 with PRIVATE slice [85][17].
// Super-step = 16 positions: 4 scalar f-loads + 4 broadcast uint4 label
// loads, double-buffered in NAMED registers (fA0..3/lA0..3 vs fB0..3/lB0..3)
// so the allocator keeps them live and the 8 next-super loads stay in flight
// during the 4 current sub-steps (~1.3 KB/wave in flight vs 256 B in R7).
// Sub-step: dup check = 6 wave-uniform compares, own label = 2 selects,
// LDS RMW (atomic fallback on dup, ~7%).
// ---------------------------------------------------------------------------
__global__ __launch_bounds__(512, 6) void k_main(const float* __restrict__ feat,
                                                 const unsigned* __restrict__ labm,
                                                 float* __restrict__ updp,
                                                 float* __restrict__ lossp, int nb) {
    __shared__ float sl[8 * SLICE_F];              // 46240 B
    __shared__ float lred[8];
    int tid = threadIdx.x;
    for (int i = tid; i < 8 * SLICE_F; i += 512) sl[i] = 0.f;
    __syncthreads();

    int lane = tid & 63;
    int w    = tid >> 6;
    int dq   = w & 3;
    int wg   = w >> 2;
    int sub  = lane >> 4;
    int l16  = lane & 15;
    float* slice = sl + w * SLICE_F;

    int ppc = BT / (nb * 2);                       // 256 when nb=768
    int p0  = (blockIdx.x * 2 + wg) * ppc;
    int nss = ppc / 16;
    const float* fbase = feat + dq * 16 + l16;

    float lsum = 0.f;
    float fA0, fA1, fA2, fA3, fB0, fB1, fB2, fB3;
    uint4 lA0, lA1, lA2, lA3, lB0, lB1, lB2, lB3;

#define ISSUE(P, f0, f1, f2, f3, q0, q1, q2, q3) do {            \
    int _p = (P);                                                \
    q0 = *(const uint4*)(labm + _p);                             \
    q1 = *(const uint4*)(labm + _p + 4);                         \
    q2 = *(const uint4*)(labm + _p + 8);                         \
    q3 = *(const uint4*)(labm + _p + 12);                        \
    f0 = fbase[(size_t)(_p + sub) * DD];                         \
    f1 = fbase[(size_t)(_p + 4 + sub) * DD];                     \
    f2 = fbase[(size_t)(_p + 8 + sub) * DD];                     \
    f3 = fbase[(size_t)(_p + 12 + sub) * DD];                    \
} while (0)

#define SUBSTEP(lv, fc) do {                                     \
    unsigned a0 = lv.x & 0x7fffffffu, a1 = lv.y & 0x7fffffffu,   \
             a2 = lv.z & 0x7fffffffu, a3 = lv.w & 0x7fffffffu;   \
    bool dup = (a0 == a1) | (a0 == a2) | (a0 == a3) |            \
               (a1 == a2) | (a1 == a3) | (a2 == a3);             \
    unsigned lw = (sub & 2) ? ((sub & 1) ? lv.w : lv.z)          \
                            : ((sub & 1) ? lv.y : lv.x);         \
    float m = (float)(lw >> 31);                                 \
    int  la = (int)(lw & 0x7fffffffu);                           \
    float c = m * (fc);                                          \
    lsum = fmaf(c, (fc), lsum);                                  \
    int a = la * 17 + l16;                                       \
    if (!dup) slice[a] += c;                                     \
    else      atomicAdd(&slice[a], c);                           \
} while (0)

    ISSUE(p0, fA0, fA1, fA2, fA3, lA0, lA1, lA2, lA3);
    for (int ss = 0; ss < nss; ss += 2) {
        if (ss + 1 < nss)
            ISSUE(p0 + (ss + 1) * 16, fB0, fB1, fB2, fB3, lB0, lB1, lB2, lB3);
        SUBSTEP(lA0, fA0); SUBSTEP(lA1, fA1);
        SUBSTEP(lA2, fA2); SUBSTEP(lA3, fA3);
        if (ss + 1 < nss) {
            if (ss + 2 < nss)
                ISSUE(p0 + (ss + 2) * 16, fA0, fA1, fA2, fA3, lA0, lA1, lA2, lA3);
            SUBSTEP(lB0, fB0); SUBSTEP(lB1, fB1);
            SUBSTEP(lB2, fB2); SUBSTEP(lB3, fB3);
        }
    }
#undef ISSUE
#undef SUBSTEP
    __syncthreads();

    float* myp = updp + (size_t)blockIdx.x * (NC * DD);
    for (int i = tid; i < NC * DD; i += 512) {
        int r = i >> 6, d = i & 63;
        int qq = d >> 4, d16 = d & 15;
        myp[i] = sl[qq * SLICE_F + r * 17 + d16] +
                 sl[(qq + 4) * SLICE_F + r * 17 + d16];
    }
#pragma unroll
    for (int off = 32; off; off >>= 1) lsum += __shfl_xor(lsum, off);
    if (lane == 0) lred[w] = lsum;
    __syncthreads();
    if (tid == 0) {
        float s = 0.f;
#pragma unroll
        for (int ww = 0; ww < 8; ++ww) s += lred[ww];
        lossp[blockIdx.x] = s;
    }
}

// ---------------------------------------------------------------------------
// Kernel 3: grid NC*4+1. Block (j,q): counts[j] = coalesced sum of
// hpartT[j][0..BB), then F over nb partials for 16 dims, write centers,
// atomic-add 0.5*loss piece into out[0]. Last block reduces Sfeat.
// ---------------------------------------------------------------------------
__global__ __launch_bounds__(256) void k_reduce(const float* __restrict__ updp,
                                                const float* __restrict__ lossp,
                                                const float* __restrict__ centers,
                                                const int* __restrict__ hpartT,
                                                float* __restrict__ out, int nb) {
    __shared__ float sred[256];
    __shared__ float sr[4];
    __shared__ int   scnt;
    int tid = threadIdx.x;
    int bid = blockIdx.x;
    if (bid < NC * 4) {
        int j = bid >> 2, q = bid & 3;
        int cs = 0;
        for (int t = tid; t < BB; t += 256) cs += hpartT[j * BB + t];
#pragma unroll
        for (int off = 32; off; off >>= 1) cs += __shfl_xor(cs, off);
        int lane = tid & 63, wv = tid >> 6;
        if (lane == 0) ((int*)sred)[wv] = cs;
        __syncthreads();
        if (tid == 0)
            scnt = ((int*)sred)[0] + ((int*)sred)[1] +
                   ((int*)sred)[2] + ((int*)sred)[3];
        __syncthreads();
        float cnt = (float)scnt;
        int i = tid & 15;
        int c16 = tid >> 4;
        int per = nb >> 4;
        int col = j * DD + q * 16 + i;
        float s = 0.f;
        for (int b = c16 * per; b < (c16 + 1) * per; ++b)
            s += updp[(size_t)b * (NC * DD) + col];
        sred[tid] = s;
        __syncthreads();
        if (tid < 16) {
            float F = 0.f;
#pragma unroll
            for (int cc = 0; cc < 16; ++cc) F += sred[cc * 16 + i];
            float c   = centers[col];
            float scale = ALPHA / (1.f + cnt);
            out[1 + col] = c - scale * (cnt * c - F);
            float lp = cnt * c * c - 2.f * c * F;
#pragma unroll
            for (int off = 8; off; off >>= 1) lp += __shfl_xor(lp, off);
            if (i == 0) atomicAdd(&out[0], 0.5f * lp);
        }
    } else {
        float s = 0.f;
        for (int t = tid; t < nb; t += 256) s += lossp[t];
#pragma unroll
        for (int off = 32; off; off >>= 1) s += __shfl_xor(s, off);
        int lane = tid & 63, wv = tid >> 6;
        if (lane == 0) sr[wv] = s;
        __syncthreads();
        if (tid == 0) atomicAdd(&out[0], 0.5f * (sr[0] + sr[1] + sr[2] + sr[3]));
    }
}

// ---------------------------------------------------------------------------
extern "C" void kernel_launch(void* const* d_in, const int* in_sizes, int n_in,
                              void* d_out, int out_size, void* d_ws, size_t ws_size,
                              hipStream_t stream) {
    const float* preds    = (const float*)d_in[0];
    const float* features = (const float*)d_in[1];
    const int*   labels   = (const int*)d_in[2];
    const float* centers  = (const float*)d_in[3];
    float* out = (float*)d_out;

    char* ws = (char*)d_ws;
    unsigned* labm = (unsigned*)ws;                             // BT words (1.5 MB)
    int* hpartT    = (int*)(ws + 4 * (size_t)BT);               // NC*BB ints (1.4 MB)
    size_t off0 = 4 * (size_t)BT + (size_t)NC * BB * 4 + 512;

    int nb = 768;
    while (nb > 16 && off0 + (size_t)nb * 4 + 512 +
                      (size_t)nb * NC * DD * 4 > ws_size)
        nb >>= 1;
    float* lossp = (float*)(ws + off0);                         // nb floats
    float* updp  = (float*)(ws + off0 + (size_t)nb * 4 + 512);

    k_amask<<<BB, 512, 0, stream>>>((const float4*)preds, labels, labm,
                                    hpartT, out);
    k_main<<<nb, 512, 0, stream>>>(features, labm, updp, lossp, nb);
    k_reduce<<<NC * 4 + 1, 256, 0, stream>>>(updp, lossp, centers, hpartT,
                                             out, nb);
}